// Round 17
// baseline (110.288 us; speedup 1.0000x reference)
//
#include <hip/hip_runtime.h>
#include <hip/hip_bf16.h>

// B=4, S=2048, D=1024, H=16, DH=64
typedef __attribute__((ext_vector_type(4))) float f32x4;
typedef __attribute__((ext_vector_type(8))) short bf16x8;
typedef __attribute__((ext_vector_type(4))) unsigned short u16x4;

#define MFMA16(a, b, c) __builtin_amdgcn_mfma_f32_16x16x32_bf16((a), (b), (c), 0, 0, 0)

static __device__ __forceinline__ unsigned short f2bf(float f) {
    unsigned u = __float_as_uint(f);
    u += 0x7FFFu + ((u >> 16) & 1u);   // RNE
    return (unsigned short)(u >> 16);
}
// pack 4 floats -> 4 bf16 (round-half-up) as uint2, via v_perm_b32
static __device__ __forceinline__ uint2 pack4_rhu(float4 v) {
    unsigned a = __float_as_uint(v.x) + 0x8000u;
    unsigned b = __float_as_uint(v.y) + 0x8000u;
    unsigned c = __float_as_uint(v.z) + 0x8000u;
    unsigned d = __float_as_uint(v.w) + 0x8000u;
    uint2 r;
    r.x = __builtin_amdgcn_perm(b, a, 0x07060302u);
    r.y = __builtin_amdgcn_perm(d, c, 0x07060302u);
    return r;
}
static __device__ __forceinline__ float exp2_fast(float x) {
#if __has_builtin(__builtin_amdgcn_exp2f)
    return __builtin_amdgcn_exp2f(x);
#else
    return exp2f(x);
#endif
}

// scores premultiplied so softmax runs in exp2 domain: c = log2(e)/32
#define QSCALE 0.04508422002778011f

// ---------------- merged prep: qproj (blocks 0..511) + k-conv (512..2559, 4x work)
// ---------------- + v-trans (2560..4607).
__global__ __launch_bounds__(256) void prep_kernel(const float* __restrict__ x,
                                                   const float* __restrict__ wq,
                                                   const float* __restrict__ kin,
                                                   const float* __restrict__ vin,
                                                   unsigned short* __restrict__ qout,
                                                   unsigned short* __restrict__ kb,
                                                   unsigned short* __restrict__ vt) {
    __shared__ __align__(16) unsigned short As[2][128][40];   // 20KB (reused by v-trans)
    __shared__ __align__(16) unsigned short Bs[2][128][40];   // 20KB
    const int bid = blockIdx.x;
    const int tid = threadIdx.x;

    if (bid < 512) {
        // ---------------- Q projection: q = (x @ Wq^T) * QSCALE, bf16 [B,H,S,DH] ----------------
        const int m0 = (bid & 63) * 128;
        const int n0 = (bid >> 6) * 128;
        const int wave = tid >> 6, lane = tid & 63;
        const int lg = lane >> 4, lc = lane & 15;
        const int wm = wave >> 1, wn = wave & 1;

        f32x4 acc[4][4];
#pragma unroll
        for (int i = 0; i < 4; ++i)
#pragma unroll
            for (int j = 0; j < 4; ++j) acc[i][j] = (f32x4){0.f, 0.f, 0.f, 0.f};

        float4 ax[4], bx[4];
#pragma unroll
        for (int i = 0; i < 4; ++i) {
            int c = tid + i * 256;
            int row = c >> 3, kc = (c & 7) * 4;
            ax[i] = *(const float4*)(x  + (size_t)(m0 + row) * 1024 + kc);
            bx[i] = *(const float4*)(wq + (size_t)(n0 + row) * 1024 + kc);
        }
#pragma unroll
        for (int i = 0; i < 4; ++i) {
            int c = tid + i * 256;
            int row = c >> 3, kc = (c & 7) * 4;
            *(uint2*)&As[0][row][kc] = pack4_rhu(ax[i]);
            *(uint2*)&Bs[0][row][kc] = pack4_rhu(bx[i]);
        }

        int cur = 0;
        for (int ki = 0; ki < 32; ++ki) {
            __syncthreads();
            const bool havenext = (ki + 1 < 32);
            if (havenext) {
                int ks = (ki + 1) * 32;
#pragma unroll
                for (int i = 0; i < 4; ++i) {
                    int c = tid + i * 256;
                    int row = c >> 3, kc = (c & 7) * 4;
                    ax[i] = *(const float4*)(x  + (size_t)(m0 + row) * 1024 + ks + kc);
                    bx[i] = *(const float4*)(wq + (size_t)(n0 + row) * 1024 + ks + kc);
                }
            }
            bf16x8 af[4], bfr[4];
#pragma unroll
            for (int i = 0; i < 4; ++i) {
                af[i]  = *(const bf16x8*)&As[cur][wm * 64 + i * 16 + lc][lg * 8];
                bfr[i] = *(const bf16x8*)&Bs[cur][wn * 64 + i * 16 + lc][lg * 8];
            }
            __builtin_amdgcn_s_setprio(1);
#pragma unroll
            for (int mi = 0; mi < 4; ++mi)
#pragma unroll
                for (int ni = 0; ni < 4; ++ni)
                    acc[mi][ni] = MFMA16(af[mi], bfr[ni], acc[mi][ni]);
            __builtin_amdgcn_s_setprio(0);
            if (havenext) {
#pragma unroll
                for (int i = 0; i < 4; ++i) {
                    int c = tid + i * 256;
                    int row = c >> 3, kc = (c & 7) * 4;
                    *(uint2*)&As[cur ^ 1][row][kc] = pack4_rhu(ax[i]);
                    *(uint2*)&Bs[cur ^ 1][row][kc] = pack4_rhu(bx[i]);
                }
            }
            cur ^= 1;
        }
#pragma unroll
        for (int mi = 0; mi < 4; ++mi)
#pragma unroll
            for (int ni = 0; ni < 4; ++ni)
#pragma unroll
                for (int r = 0; r < 4; ++r) {
                    int m = m0 + wm * 64 + mi * 16 + lg * 4 + r;
                    int n = n0 + wn * 64 + ni * 16 + lc;
                    int b = m >> 11, s = m & 2047;
                    int h = n >> 6, dh = n & 63;
                    qout[(((size_t)b * 16 + h) * 2048 + s) * 64 + dh] = f2bf(acc[mi][ni][r] * QSCALE);
                }
    } else if (bid < 512 + 2048) {
        // ---------------- k fp32 -> bf16 : 4 independent strided chunks ----------------
        const int base = (bid - 512) * 256 + tid;     // 0..524287
        float4 v0 = ((const float4*)kin)[base];
        float4 v1 = ((const float4*)kin)[base + 524288];
        float4 v2 = ((const float4*)kin)[base + 1048576];
        float4 v3 = ((const float4*)kin)[base + 1572864];
        *(uint2*)&((u16x4*)kb)[base]           = pack4_rhu(v0);
        *(uint2*)&((u16x4*)kb)[base + 524288]  = pack4_rhu(v1);
        *(uint2*)&((u16x4*)kb)[base + 1048576] = pack4_rhu(v2);
        *(uint2*)&((u16x4*)kb)[base + 1572864] = pack4_rhu(v3);
    } else {
        // ---------------- v fp32 [B,H,S,DH] -> bf16 [B,H,DH,S] ----------------
        float (*buf)[65] = (float (*)[65])(&As[0][0][0]);   // 16.6KB, fits in As
        const int idx = bid - (512 + 2048);
        const int s0 = (idx & 31) * 64;
        const int bh = idx >> 5;
#pragma unroll
        for (int i = 0; i < 4; ++i) {
            int c = tid + i * 256;
            int s = c >> 4, dc = (c & 15) * 4;
            float4 val = *(const float4*)(vin + ((size_t)bh * 2048 + s0 + s) * 64 + dc);
            buf[s][dc] = val.x; buf[s][dc + 1] = val.y; buf[s][dc + 2] = val.z; buf[s][dc + 3] = val.w;
        }
        __syncthreads();
#pragma unroll
        for (int i = 0; i < 4; ++i) {
            int c = tid + i * 256;
            int dh = c >> 4, sc = (c & 15) * 4;
            u16x4 o = { f2bf(buf[sc][dh]), f2bf(buf[sc + 1][dh]), f2bf(buf[sc + 2][dh]), f2bf(buf[sc + 3][dh]) };
            *(u16x4*)(vt + ((size_t)bh * 64 + dh) * 2048 + s0 + sc) = o;
        }
    }
}

// ---------------- fused causal flash attention + residual ----------------
// grid: (64 bh, 32), qblk = 31 - blockIdx.y (LPT). 128 threads = 2 waves x 32
// q-rows = one 64-row q-block per block; nkv = qblk+1; ZERO inactive wave-iters
// (every wave's diagonal is the block's last tile). SINGLE-buffered K/VT + Ps
// = 25.2KB -> 6 blocks/CU, 1536 slots < 2048 blocks = real backfill queue at
// ~12 waves/CU. 2 barriers/iter, async-split staging (loads before compute,
// ds_write after 2nd barrier). Per-wave body identical to the proven R10 kernel:
// swapped QK^T & PV, no-max exp2 softmax, deferred l, vec4 epilogue.
__global__ __launch_bounds__(128) void attn_kernel(const unsigned short* __restrict__ qg,
                                                   const unsigned short* __restrict__ kg,
                                                   const unsigned short* __restrict__ vtg,
                                                   const float* __restrict__ x,
                                                   float* __restrict__ outp) {
    __shared__ __align__(16) unsigned short Ks[64][64];
    __shared__ __align__(16) unsigned short VTs[64][64];
    __shared__ __align__(16) unsigned short Ps[2][32][72];

    const int bh = blockIdx.x;
    const int qblk = 31 - blockIdx.y;
    const int b = bh >> 4, h = bh & 15;
    const int tid = threadIdx.x;           // 0..127
    const int wave = tid >> 6, lane = tid & 63;
    const int lg = lane >> 4, lc = lane & 15;
    const int lc7 = lc & 7;
    const int qw0 = qblk * 64 + wave * 32;
    const int nkv = qblk + 1;

    // staging: 128 threads x 4 chunks each for K and VT (row sr, chunks cb..cb+3)
    const int sr = tid >> 1;               // 0..63
    const int cb = (tid & 1) * 4;          // 16B-chunk base: 0 or 4
    int swz[4];
#pragma unroll
    for (int j = 0; j < 4; ++j) swz[j] = ((cb + j) ^ (sr & 7)) * 8;
    const unsigned short* kbase = kg  + ((size_t)bh * 2048 + sr) * 64;
    const unsigned short* vbase = vtg + ((size_t)bh * 64 + sr) * 2048;

    // Q B-frags in registers: qf[qt][c] = Q[qw0+qt*16+lc][c*32 + lg*8 ..]
    bf16x8 qf[2][2];
#pragma unroll
    for (int qt = 0; qt < 2; ++qt)
#pragma unroll
        for (int c = 0; c < 2; ++c)
            qf[qt][c] = *(const bf16x8*)(qg + ((size_t)bh * 2048 + qw0 + qt * 16 + lc) * 64 + c * 32 + lg * 8);

    f32x4 oacc[2][4];   // O^T: col=lc=q-local, row=lg*4+r=dh-local
#pragma unroll
    for (int qt = 0; qt < 2; ++qt)
#pragma unroll
        for (int dt = 0; dt < 4; ++dt) oacc[qt][dt] = (f32x4){0.f, 0.f, 0.f, 0.f};
    float l_r[2] = {0.f, 0.f};   // lane-local partials; cross-group reduce in epilogue

    {   // prologue: stage tile 0
#pragma unroll
        for (int j = 0; j < 4; ++j) {
            *(bf16x8*)&Ks[sr][swz[j]]  = *(const bf16x8*)(kbase + (cb + j) * 8);
            *(bf16x8*)&VTs[sr][swz[j]] = *(const bf16x8*)(vbase + (cb + j) * 8);
        }
    }

    for (int kv = 0; kv < nkv; ++kv) {
        __syncthreads();   // tile kv staged & visible

        const bool havenext = (kv + 1 < nkv);
        const int nxt = havenext ? kv + 1 : kv;
        bf16x8 nk[4], nv[4];
#pragma unroll
        for (int j = 0; j < 4; ++j) {
            nk[j] = *(const bf16x8*)(kbase + (size_t)nxt * 4096 + (cb + j) * 8);
            nv[j] = *(const bf16x8*)(vbase + nxt * 64 + (cb + j) * 8);
        }

        // K A-frags (shared across both q-tiles)
        bf16x8 kf[4][2];
#pragma unroll
        for (int kt = 0; kt < 4; ++kt)
#pragma unroll
            for (int c = 0; c < 2; ++c)
                kf[kt][c] = *(const bf16x8*)&Ks[kt * 16 + lc][((4 * c + lg) ^ lc7) * 8];

        const int kvb = kv * 64;
        // ---- per q-tile: S^T = K Q^T (8 MFMA), softmax, pack -> Ps ----
#pragma unroll
        for (int qt = 0; qt < 2; ++qt) {
            f32x4 st[4];
            __builtin_amdgcn_s_setprio(1);
#pragma unroll
            for (int kt = 0; kt < 4; ++kt) {
                f32x4 a = (f32x4){0.f, 0.f, 0.f, 0.f};
                a = MFMA16(kf[kt][0], qf[qt][0], a);
                a = MFMA16(kf[kt][1], qf[qt][1], a);
                st[kt] = a;
            }
            __builtin_amdgcn_s_setprio(0);

            float pp[4][4];
#pragma unroll
            for (int kt = 0; kt < 4; ++kt)
#pragma unroll
                for (int r = 0; r < 4; ++r) pp[kt][r] = st[kt][r];
            if (kvb + 63 > qw0 + qt * 16) {   // diagonal tile only
                const int qrow = qw0 + qt * 16 + lc;
#pragma unroll
                for (int kt = 0; kt < 4; ++kt)
#pragma unroll
                    for (int r = 0; r < 4; ++r) {
                        int kk = kvb + kt * 16 + lg * 4 + r;
                        if (kk > qrow) pp[kt][r] = -1e30f;
                    }
            }
            float rs = 0.f;
#pragma unroll
            for (int kt = 0; kt < 4; ++kt)
#pragma unroll
                for (int r = 0; r < 4; ++r) {
                    float e = exp2_fast(pp[kt][r]);
                    pp[kt][r] = e;
                    rs += e;
                }
            l_r[qt] += rs;
#pragma unroll
            for (int kt = 0; kt < 4; ++kt) {
                uint2 w;
                w.x = __builtin_amdgcn_perm(__float_as_uint(pp[kt][1]), __float_as_uint(pp[kt][0]), 0x07060302u);
                w.y = __builtin_amdgcn_perm(__float_as_uint(pp[kt][3]), __float_as_uint(pp[kt][2]), 0x07060302u);
                *(uint2*)&Ps[wave][qt * 16 + lc][kt * 16 + lg * 4] = w;
            }
        }
        asm volatile("s_waitcnt lgkmcnt(0)" ::: "memory");

        // ---- O^T += V^T P^T : 16 MFMA, vtf shared across q-tiles ----
        bf16x8 pf[2][2];
#pragma unroll
        for (int qt = 0; qt < 2; ++qt)
#pragma unroll
            for (int c = 0; c < 2; ++c)
                pf[qt][c] = *(const bf16x8*)&Ps[wave][qt * 16 + lc][c * 32 + lg * 8];
        __builtin_amdgcn_s_setprio(1);
#pragma unroll
        for (int dt = 0; dt < 4; ++dt)
#pragma unroll
            for (int c = 0; c < 2; ++c) {
                bf16x8 vtf = *(const bf16x8*)&VTs[dt * 16 + lc][((4 * c + lg) ^ lc7) * 8];
#pragma unroll
                for (int qt = 0; qt < 2; ++qt)
                    oacc[qt][dt] = MFMA16(vtf, pf[qt][c], oacc[qt][dt]);
            }
        __builtin_amdgcn_s_setprio(0);

        __syncthreads();   // all reads of tile kv done
        if (havenext) {
#pragma unroll
            for (int j = 0; j < 4; ++j) {
                *(bf16x8*)&Ks[sr][swz[j]]  = nk[j];
                *(bf16x8*)&VTs[sr][swz[j]] = nv[j];
            }
        }
    }

    // epilogue: finish l reduction, normalize, add residual, vec4 store
#pragma unroll
    for (int qt = 0; qt < 2; ++qt) {
        float lt = l_r[qt];
        lt += __shfl_xor(lt, 16, 64);
        lt += __shfl_xor(lt, 32, 64);
        float li = 1.0f / lt;
        const int q = qw0 + qt * 16 + lc;
        const size_t obase = ((size_t)b * 2048 + q) * 1024 + (size_t)h * 64 + lg * 4;
#pragma unroll
        for (int dt = 0; dt < 4; ++dt) {
            const size_t oi = obase + dt * 16;
            float4 xv = *(const float4*)(x + oi);
            float4 ov;
            ov.x = xv.x + oacc[qt][dt][0] * li;
            ov.y = xv.y + oacc[qt][dt][1] * li;
            ov.z = xv.z + oacc[qt][dt][2] * li;
            ov.w = xv.w + oacc[qt][dt][3] * li;
            *(float4*)(outp + oi) = ov;
        }
    }
}

extern "C" void kernel_launch(void* const* d_in, const int* in_sizes, int n_in,
                              void* d_out, int out_size, void* d_ws, size_t ws_size,
                              hipStream_t stream) {
    const float* x  = (const float*)d_in[0];
    const float* k  = (const float*)d_in[1];
    const float* v  = (const float*)d_in[2];
    const float* wq = (const float*)d_in[3];
    float* outp = (float*)d_out;

    const size_t NELEM = (size_t)4 * 2048 * 1024;
    unsigned short* qbuf = (unsigned short*)d_ws;
    unsigned short* kbuf = qbuf + NELEM;
    unsigned short* vtbuf = kbuf + NELEM;

    // merged prep: 512 qproj + 2048 k-conv (4x work each) + 2048 v-trans
    prep_kernel<<<512 + 2048 + 2048, 256, 0, stream>>>(x, wq, k, v, qbuf, kbuf, vtbuf);
    attn_kernel<<<dim3(64, 32), 128, 0, stream>>>(qbuf, kbuf, vtbuf, x, outp);
}

// Round 18
// 96.123 us; speedup vs baseline: 1.1474x; 1.1474x over previous
//
#include <hip/hip_runtime.h>
#include <hip/hip_bf16.h>

// B=4, S=2048, D=1024, H=16, DH=64
typedef __attribute__((ext_vector_type(4))) float f32x4;
typedef __attribute__((ext_vector_type(8))) short bf16x8;
typedef __attribute__((ext_vector_type(4))) unsigned short u16x4;

#define MFMA16(a, b, c) __builtin_amdgcn_mfma_f32_16x16x32_bf16((a), (b), (c), 0, 0, 0)

static __device__ __forceinline__ unsigned short f2bf(float f) {
    unsigned u = __float_as_uint(f);
    u += 0x7FFFu + ((u >> 16) & 1u);   // RNE
    return (unsigned short)(u >> 16);
}
// pack 4 floats -> 4 bf16 (round-half-up) as uint2, via v_perm_b32
static __device__ __forceinline__ uint2 pack4_rhu(float4 v) {
    unsigned a = __float_as_uint(v.x) + 0x8000u;
    unsigned b = __float_as_uint(v.y) + 0x8000u;
    unsigned c = __float_as_uint(v.z) + 0x8000u;
    unsigned d = __float_as_uint(v.w) + 0x8000u;
    uint2 r;
    r.x = __builtin_amdgcn_perm(b, a, 0x07060302u);
    r.y = __builtin_amdgcn_perm(d, c, 0x07060302u);
    return r;
}
static __device__ __forceinline__ float exp2_fast(float x) {
#if __has_builtin(__builtin_amdgcn_exp2f)
    return __builtin_amdgcn_exp2f(x);
#else
    return exp2f(x);
#endif
}

// scores premultiplied so softmax runs in exp2 domain: c = log2(e)/32
#define QSCALE 0.04508422002778011f

// ---------------- merged prep: qproj (blocks 0..511) + k-conv (512..2559, 4x work)
// ---------------- + v-trans (2560..4607).
__global__ __launch_bounds__(256) void prep_kernel(const float* __restrict__ x,
                                                   const float* __restrict__ wq,
                                                   const float* __restrict__ kin,
                                                   const float* __restrict__ vin,
                                                   unsigned short* __restrict__ qout,
                                                   unsigned short* __restrict__ kb,
                                                   unsigned short* __restrict__ vt) {
    __shared__ __align__(16) unsigned short As[2][128][40];   // 20KB (reused by v-trans)
    __shared__ __align__(16) unsigned short Bs[2][128][40];   // 20KB
    const int bid = blockIdx.x;
    const int tid = threadIdx.x;

    if (bid < 512) {
        // ---------------- Q projection: q = (x @ Wq^T) * QSCALE, bf16 [B,H,S,DH] ----------------
        const int m0 = (bid & 63) * 128;
        const int n0 = (bid >> 6) * 128;
        const int wave = tid >> 6, lane = tid & 63;
        const int lg = lane >> 4, lc = lane & 15;
        const int wm = wave >> 1, wn = wave & 1;

        f32x4 acc[4][4];
#pragma unroll
        for (int i = 0; i < 4; ++i)
#pragma unroll
            for (int j = 0; j < 4; ++j) acc[i][j] = (f32x4){0.f, 0.f, 0.f, 0.f};

        float4 ax[4], bx[4];
#pragma unroll
        for (int i = 0; i < 4; ++i) {
            int c = tid + i * 256;
            int row = c >> 3, kc = (c & 7) * 4;
            ax[i] = *(const float4*)(x  + (size_t)(m0 + row) * 1024 + kc);
            bx[i] = *(const float4*)(wq + (size_t)(n0 + row) * 1024 + kc);
        }
#pragma unroll
        for (int i = 0; i < 4; ++i) {
            int c = tid + i * 256;
            int row = c >> 3, kc = (c & 7) * 4;
            *(uint2*)&As[0][row][kc] = pack4_rhu(ax[i]);
            *(uint2*)&Bs[0][row][kc] = pack4_rhu(bx[i]);
        }

        int cur = 0;
        for (int ki = 0; ki < 32; ++ki) {
            __syncthreads();
            const bool havenext = (ki + 1 < 32);
            if (havenext) {
                int ks = (ki + 1) * 32;
#pragma unroll
                for (int i = 0; i < 4; ++i) {
                    int c = tid + i * 256;
                    int row = c >> 3, kc = (c & 7) * 4;
                    ax[i] = *(const float4*)(x  + (size_t)(m0 + row) * 1024 + ks + kc);
                    bx[i] = *(const float4*)(wq + (size_t)(n0 + row) * 1024 + ks + kc);
                }
            }
            bf16x8 af[4], bfr[4];
#pragma unroll
            for (int i = 0; i < 4; ++i) {
                af[i]  = *(const bf16x8*)&As[cur][wm * 64 + i * 16 + lc][lg * 8];
                bfr[i] = *(const bf16x8*)&Bs[cur][wn * 64 + i * 16 + lc][lg * 8];
            }
            __builtin_amdgcn_s_setprio(1);
#pragma unroll
            for (int mi = 0; mi < 4; ++mi)
#pragma unroll
                for (int ni = 0; ni < 4; ++ni)
                    acc[mi][ni] = MFMA16(af[mi], bfr[ni], acc[mi][ni]);
            __builtin_amdgcn_s_setprio(0);
            if (havenext) {
#pragma unroll
                for (int i = 0; i < 4; ++i) {
                    int c = tid + i * 256;
                    int row = c >> 3, kc = (c & 7) * 4;
                    *(uint2*)&As[cur ^ 1][row][kc] = pack4_rhu(ax[i]);
                    *(uint2*)&Bs[cur ^ 1][row][kc] = pack4_rhu(bx[i]);
                }
            }
            cur ^= 1;
        }
#pragma unroll
        for (int mi = 0; mi < 4; ++mi)
#pragma unroll
            for (int ni = 0; ni < 4; ++ni)
#pragma unroll
                for (int r = 0; r < 4; ++r) {
                    int m = m0 + wm * 64 + mi * 16 + lg * 4 + r;
                    int n = n0 + wn * 64 + ni * 16 + lc;
                    int b = m >> 11, s = m & 2047;
                    int h = n >> 6, dh = n & 63;
                    qout[(((size_t)b * 16 + h) * 2048 + s) * 64 + dh] = f2bf(acc[mi][ni][r] * QSCALE);
                }
    } else if (bid < 512 + 2048) {
        // ---------------- k fp32 -> bf16 : 4 independent strided chunks ----------------
        const int base = (bid - 512) * 256 + tid;     // 0..524287
        float4 v0 = ((const float4*)kin)[base];
        float4 v1 = ((const float4*)kin)[base + 524288];
        float4 v2 = ((const float4*)kin)[base + 1048576];
        float4 v3 = ((const float4*)kin)[base + 1572864];
        *(uint2*)&((u16x4*)kb)[base]           = pack4_rhu(v0);
        *(uint2*)&((u16x4*)kb)[base + 524288]  = pack4_rhu(v1);
        *(uint2*)&((u16x4*)kb)[base + 1048576] = pack4_rhu(v2);
        *(uint2*)&((u16x4*)kb)[base + 1572864] = pack4_rhu(v3);
    } else {
        // ---------------- v fp32 [B,H,S,DH] -> bf16 [B,H,DH,S] ----------------
        float (*buf)[65] = (float (*)[65])(&As[0][0][0]);   // 16.6KB, fits in As
        const int idx = bid - (512 + 2048);
        const int s0 = (idx & 31) * 64;
        const int bh = idx >> 5;
#pragma unroll
        for (int i = 0; i < 4; ++i) {
            int c = tid + i * 256;
            int s = c >> 4, dc = (c & 15) * 4;
            float4 val = *(const float4*)(vin + ((size_t)bh * 2048 + s0 + s) * 64 + dc);
            buf[s][dc] = val.x; buf[s][dc + 1] = val.y; buf[s][dc + 2] = val.z; buf[s][dc + 3] = val.w;
        }
        __syncthreads();
#pragma unroll
        for (int i = 0; i < 4; ++i) {
            int c = tid + i * 256;
            int dh = c >> 4, sc = (c & 15) * 4;
            u16x4 o = { f2bf(buf[sc][dh]), f2bf(buf[sc + 1][dh]), f2bf(buf[sc + 2][dh]), f2bf(buf[sc + 3][dh]) };
            *(u16x4*)(vt + ((size_t)bh * 64 + dh) * 2048 + s0 + sc) = o;
        }
    }
}

// ---------------- fused causal flash attention + residual (R10 body) ----------------
// grid: (64 bh, 16), qb = 15 - blockIdx.y -> LPT dispatch (longest first, x fastest).
// 256 threads (4 waves) x 32 q-rows = one 128-row q-block per block.
// LDS 51KB (double-buffered K/VT + Ps) -> 3 blocks/CU: 768 slots < 1024 blocks
// = real backfill queue holding the shortest blocks.
// Ps padded to 76 (152B stride = 6*lc mod 32, a permutation over the 16-lane
// group) -> b128 Ps reads bank-conflict-free (R10's 72-pad aliased 4-8 way;
// all 3.24M conflict cycles were Ps traffic per R11's zero-conflict control).
// One barrier/iter: issue loads(next) after barrier, compute(cur), ds_write(next).
// Swapped QK^T & PV; no-max exp2 softmax; deferred l-reduction; vec4 epilogue.
__global__ __launch_bounds__(256, 3) void attn_kernel(const unsigned short* __restrict__ qg,
                                                      const unsigned short* __restrict__ kg,
                                                      const unsigned short* __restrict__ vtg,
                                                      const float* __restrict__ x,
                                                      float* __restrict__ outp) {
    __shared__ __align__(16) unsigned short Ks[2][64][64];
    __shared__ __align__(16) unsigned short VTs[2][64][64];
    __shared__ __align__(16) unsigned short Ps[4][32][76];

    const int bh = blockIdx.x;
    const int qb = 15 - blockIdx.y;
    const int b = bh >> 4, h = bh & 15;
    const int tid = threadIdx.x;
    const int wave = tid >> 6, lane = tid & 63;
    const int lg = lane >> 4, lc = lane & 15;
    const int lc7 = lc & 7;
    const int qw0 = qb * 128 + wave * 32;
    const int nkv = 2 * qb + 2;

    // staging: 256 threads cover 512 chunks of K and VT (2 rows each, same c16)
    const int r0  = tid >> 3;            // 0..31
    const int c16 = tid & 7;
    const int swz = (c16 ^ (r0 & 7)) * 8;    // same for r0+32 (low 3 bits equal)
    const unsigned short* kbase = kg  + ((size_t)bh * 2048 + r0) * 64 + c16 * 8;
    const unsigned short* vbase = vtg + ((size_t)bh * 64 + r0) * 2048 + c16 * 8;

    // Q B-frags in registers: qf[qt][c] = Q[qw0+qt*16+lc][c*32 + lg*8 ..]
    bf16x8 qf[2][2];
#pragma unroll
    for (int qt = 0; qt < 2; ++qt)
#pragma unroll
        for (int c = 0; c < 2; ++c)
            qf[qt][c] = *(const bf16x8*)(qg + ((size_t)bh * 2048 + qw0 + qt * 16 + lc) * 64 + c * 32 + lg * 8);

    f32x4 oacc[2][4];   // O^T: col=lc=q-local, row=lg*4+r=dh-local
#pragma unroll
    for (int qt = 0; qt < 2; ++qt)
#pragma unroll
        for (int dt = 0; dt < 4; ++dt) oacc[qt][dt] = (f32x4){0.f, 0.f, 0.f, 0.f};
    float l_r[2] = {0.f, 0.f};   // lane-local partials; cross-group reduce in epilogue

    {   // prologue: stage tile 0 into buffer 0
        *(bf16x8*)&Ks[0][r0][swz]       = *(const bf16x8*)(kbase);
        *(bf16x8*)&Ks[0][r0 + 32][swz]  = *(const bf16x8*)(kbase + 2048);
        *(bf16x8*)&VTs[0][r0][swz]      = *(const bf16x8*)(vbase);
        *(bf16x8*)&VTs[0][r0 + 32][swz] = *(const bf16x8*)(vbase + 65536);
    }

    int cur = 0;
    for (int kv = 0; kv < nkv; ++kv) {
        __syncthreads();   // buf[cur] staged & visible; buf[cur^1] readers done

        const bool havenext = (kv + 1 < nkv);
        const int nxt = havenext ? kv + 1 : kv;
        bf16x8 nk0 = *(const bf16x8*)(kbase + (size_t)nxt * 4096);
        bf16x8 nk1 = *(const bf16x8*)(kbase + (size_t)nxt * 4096 + 2048);
        bf16x8 nv0 = *(const bf16x8*)(vbase + nxt * 64);
        bf16x8 nv1 = *(const bf16x8*)(vbase + nxt * 64 + 65536);

        const bool active = (kv * 64 <= qw0 + 31);
        if (active) {
            // K A-frags (shared across both q-tiles)
            bf16x8 kf[4][2];
#pragma unroll
            for (int kt = 0; kt < 4; ++kt)
#pragma unroll
                for (int c = 0; c < 2; ++c)
                    kf[kt][c] = *(const bf16x8*)&Ks[cur][kt * 16 + lc][((4 * c + lg) ^ lc7) * 8];

            const int kvb = kv * 64;
            // ---- per q-tile: S^T = K Q^T (8 MFMA), softmax, pack -> Ps ----
#pragma unroll
            for (int qt = 0; qt < 2; ++qt) {
                f32x4 st[4];
                __builtin_amdgcn_s_setprio(1);
#pragma unroll
                for (int kt = 0; kt < 4; ++kt) {
                    f32x4 a = (f32x4){0.f, 0.f, 0.f, 0.f};
                    a = MFMA16(kf[kt][0], qf[qt][0], a);
                    a = MFMA16(kf[kt][1], qf[qt][1], a);
                    st[kt] = a;
                }
                __builtin_amdgcn_s_setprio(0);

                float pp[4][4];
#pragma unroll
                for (int kt = 0; kt < 4; ++kt)
#pragma unroll
                    for (int r = 0; r < 4; ++r) pp[kt][r] = st[kt][r];
                if (kvb + 63 > qw0 + qt * 16) {   // diagonal tile only
                    const int qrow = qw0 + qt * 16 + lc;
#pragma unroll
                    for (int kt = 0; kt < 4; ++kt)
#pragma unroll
                        for (int r = 0; r < 4; ++r) {
                            int kk = kvb + kt * 16 + lg * 4 + r;
                            if (kk > qrow) pp[kt][r] = -1e30f;
                        }
                }
                float rs = 0.f;
#pragma unroll
                for (int kt = 0; kt < 4; ++kt)
#pragma unroll
                    for (int r = 0; r < 4; ++r) {
                        float e = exp2_fast(pp[kt][r]);
                        pp[kt][r] = e;
                        rs += e;
                    }
                l_r[qt] += rs;
#pragma unroll
                for (int kt = 0; kt < 4; ++kt) {
                    uint2 w;
                    w.x = __builtin_amdgcn_perm(__float_as_uint(pp[kt][1]), __float_as_uint(pp[kt][0]), 0x07060302u);
                    w.y = __builtin_amdgcn_perm(__float_as_uint(pp[kt][3]), __float_as_uint(pp[kt][2]), 0x07060302u);
                    *(uint2*)&Ps[wave][qt * 16 + lc][kt * 16 + lg * 4] = w;
                }
            }
            asm volatile("s_waitcnt lgkmcnt(0)" ::: "memory");

            // ---- O^T += V^T P^T : 16 MFMA, vtf shared across q-tiles ----
            bf16x8 pf[2][2];
#pragma unroll
            for (int qt = 0; qt < 2; ++qt)
#pragma unroll
                for (int c = 0; c < 2; ++c)
                    pf[qt][c] = *(const bf16x8*)&Ps[wave][qt * 16 + lc][c * 32 + lg * 8];
            __builtin_amdgcn_s_setprio(1);
#pragma unroll
            for (int dt = 0; dt < 4; ++dt)
#pragma unroll
                for (int c = 0; c < 2; ++c) {
                    bf16x8 vtf = *(const bf16x8*)&VTs[cur][dt * 16 + lc][((4 * c + lg) ^ lc7) * 8];
#pragma unroll
                    for (int qt = 0; qt < 2; ++qt)
                        oacc[qt][dt] = MFMA16(vtf, pf[qt][c], oacc[qt][dt]);
                }
            __builtin_amdgcn_s_setprio(0);
        }

        // write next tile into the other buffer (nobody reads it until next barrier)
        if (havenext) {
            *(bf16x8*)&Ks[cur ^ 1][r0][swz]       = nk0;
            *(bf16x8*)&Ks[cur ^ 1][r0 + 32][swz]  = nk1;
            *(bf16x8*)&VTs[cur ^ 1][r0][swz]      = nv0;
            *(bf16x8*)&VTs[cur ^ 1][r0 + 32][swz] = nv1;
        }
        cur ^= 1;
    }

    // epilogue: finish l reduction, normalize, add residual, vec4 store
#pragma unroll
    for (int qt = 0; qt < 2; ++qt) {
        float lt = l_r[qt];
        lt += __shfl_xor(lt, 16, 64);
        lt += __shfl_xor(lt, 32, 64);
        float li = 1.0f / lt;
        const int q = qw0 + qt * 16 + lc;
        const size_t obase = ((size_t)b * 2048 + q) * 1024 + (size_t)h * 64 + lg * 4;
#pragma unroll
        for (int dt = 0; dt < 4; ++dt) {
            const size_t oi = obase + dt * 16;
            float4 xv = *(const float4*)(x + oi);
            float4 ov;
            ov.x = xv.x + oacc[qt][dt][0] * li;
            ov.y = xv.y + oacc[qt][dt][1] * li;
            ov.z = xv.z + oacc[qt][dt][2] * li;
            ov.w = xv.w + oacc[qt][dt][3] * li;
            *(float4*)(outp + oi) = ov;
        }
    }
}

extern "C" void kernel_launch(void* const* d_in, const int* in_sizes, int n_in,
                              void* d_out, int out_size, void* d_ws, size_t ws_size,
                              hipStream_t stream) {
    const float* x  = (const float*)d_in[0];
    const float* k  = (const float*)d_in[1];
    const float* v  = (const float*)d_in[2];
    const float* wq = (const float*)d_in[3];
    float* outp = (float*)d_out;

    const size_t NELEM = (size_t)4 * 2048 * 1024;
    unsigned short* qbuf = (unsigned short*)d_ws;
    unsigned short* kbuf = qbuf + NELEM;
    unsigned short* vtbuf = kbuf + NELEM;

    // merged prep: 512 qproj + 2048 k-conv (4x work each) + 2048 v-trans
    prep_kernel<<<512 + 2048 + 2048, 256, 0, stream>>>(x, wq, k, v, qbuf, kbuf, vtbuf);
    attn_kernel<<<dim3(64, 16), 256, 0, stream>>>(qbuf, kbuf, vtbuf, x, outp);
}

// Round 19
// 91.818 us; speedup vs baseline: 1.2012x; 1.0469x over previous
//
#include <hip/hip_runtime.h>
#include <hip/hip_bf16.h>

// B=4, S=2048, D=1024, H=16, DH=64
typedef __attribute__((ext_vector_type(4))) float f32x4;
typedef __attribute__((ext_vector_type(8))) short bf16x8;
typedef __attribute__((ext_vector_type(4))) unsigned short u16x4;

#define MFMA16(a, b, c) __builtin_amdgcn_mfma_f32_16x16x32_bf16((a), (b), (c), 0, 0, 0)

static __device__ __forceinline__ unsigned short f2bf(float f) {
    unsigned u = __float_as_uint(f);
    u += 0x7FFFu + ((u >> 16) & 1u);   // RNE
    return (unsigned short)(u >> 16);
}
// pack 4 floats -> 4 bf16 (round-half-up) as uint2, via v_perm_b32
static __device__ __forceinline__ uint2 pack4_rhu(float4 v) {
    unsigned a = __float_as_uint(v.x) + 0x8000u;
    unsigned b = __float_as_uint(v.y) + 0x8000u;
    unsigned c = __float_as_uint(v.z) + 0x8000u;
    unsigned d = __float_as_uint(v.w) + 0x8000u;
    uint2 r;
    r.x = __builtin_amdgcn_perm(b, a, 0x07060302u);
    r.y = __builtin_amdgcn_perm(d, c, 0x07060302u);
    return r;
}
static __device__ __forceinline__ float exp2_fast(float x) {
#if __has_builtin(__builtin_amdgcn_exp2f)
    return __builtin_amdgcn_exp2f(x);
#else
    return exp2f(x);
#endif
}

// scores premultiplied so softmax runs in exp2 domain: c = log2(e)/32
#define QSCALE 0.04508422002778011f

// ---------------- merged prep: qproj (blocks 0..511) + v-trans (512..2559) ----------------
// k-conversion ELIMINATED: attn stages K directly from fp32 (saves 48MB HBM).
__global__ __launch_bounds__(256) void prep_kernel(const float* __restrict__ x,
                                                   const float* __restrict__ wq,
                                                   const float* __restrict__ vin,
                                                   unsigned short* __restrict__ qout,
                                                   unsigned short* __restrict__ vt) {
    __shared__ __align__(16) unsigned short As[2][128][40];   // 20KB (reused by v-trans)
    __shared__ __align__(16) unsigned short Bs[2][128][40];   // 20KB
    const int bid = blockIdx.x;
    const int tid = threadIdx.x;

    if (bid < 512) {
        // ---------------- Q projection: q = (x @ Wq^T) * QSCALE, bf16 [B,H,S,DH] ----------------
        const int m0 = (bid & 63) * 128;
        const int n0 = (bid >> 6) * 128;
        const int wave = tid >> 6, lane = tid & 63;
        const int lg = lane >> 4, lc = lane & 15;
        const int wm = wave >> 1, wn = wave & 1;

        f32x4 acc[4][4];
#pragma unroll
        for (int i = 0; i < 4; ++i)
#pragma unroll
            for (int j = 0; j < 4; ++j) acc[i][j] = (f32x4){0.f, 0.f, 0.f, 0.f};

        float4 ax[4], bx[4];
#pragma unroll
        for (int i = 0; i < 4; ++i) {
            int c = tid + i * 256;
            int row = c >> 3, kc = (c & 7) * 4;
            ax[i] = *(const float4*)(x  + (size_t)(m0 + row) * 1024 + kc);
            bx[i] = *(const float4*)(wq + (size_t)(n0 + row) * 1024 + kc);
        }
#pragma unroll
        for (int i = 0; i < 4; ++i) {
            int c = tid + i * 256;
            int row = c >> 3, kc = (c & 7) * 4;
            *(uint2*)&As[0][row][kc] = pack4_rhu(ax[i]);
            *(uint2*)&Bs[0][row][kc] = pack4_rhu(bx[i]);
        }

        int cur = 0;
        for (int ki = 0; ki < 32; ++ki) {
            __syncthreads();
            const bool havenext = (ki + 1 < 32);
            if (havenext) {
                int ks = (ki + 1) * 32;
#pragma unroll
                for (int i = 0; i < 4; ++i) {
                    int c = tid + i * 256;
                    int row = c >> 3, kc = (c & 7) * 4;
                    ax[i] = *(const float4*)(x  + (size_t)(m0 + row) * 1024 + ks + kc);
                    bx[i] = *(const float4*)(wq + (size_t)(n0 + row) * 1024 + ks + kc);
                }
            }
            bf16x8 af[4], bfr[4];
#pragma unroll
            for (int i = 0; i < 4; ++i) {
                af[i]  = *(const bf16x8*)&As[cur][wm * 64 + i * 16 + lc][lg * 8];
                bfr[i] = *(const bf16x8*)&Bs[cur][wn * 64 + i * 16 + lc][lg * 8];
            }
            __builtin_amdgcn_s_setprio(1);
#pragma unroll
            for (int mi = 0; mi < 4; ++mi)
#pragma unroll
                for (int ni = 0; ni < 4; ++ni)
                    acc[mi][ni] = MFMA16(af[mi], bfr[ni], acc[mi][ni]);
            __builtin_amdgcn_s_setprio(0);
            if (havenext) {
#pragma unroll
                for (int i = 0; i < 4; ++i) {
                    int c = tid + i * 256;
                    int row = c >> 3, kc = (c & 7) * 4;
                    *(uint2*)&As[cur ^ 1][row][kc] = pack4_rhu(ax[i]);
                    *(uint2*)&Bs[cur ^ 1][row][kc] = pack4_rhu(bx[i]);
                }
            }
            cur ^= 1;
        }
#pragma unroll
        for (int mi = 0; mi < 4; ++mi)
#pragma unroll
            for (int ni = 0; ni < 4; ++ni)
#pragma unroll
                for (int r = 0; r < 4; ++r) {
                    int m = m0 + wm * 64 + mi * 16 + lg * 4 + r;
                    int n = n0 + wn * 64 + ni * 16 + lc;
                    int b = m >> 11, s = m & 2047;
                    int h = n >> 6, dh = n & 63;
                    qout[(((size_t)b * 16 + h) * 2048 + s) * 64 + dh] = f2bf(acc[mi][ni][r] * QSCALE);
                }
    } else {
        // ---------------- v fp32 [B,H,S,DH] -> bf16 [B,H,DH,S] ----------------
        float (*buf)[65] = (float (*)[65])(&As[0][0][0]);   // 16.6KB, fits in As
        const int idx = bid - 512;
        const int s0 = (idx & 31) * 64;
        const int bh = idx >> 5;
#pragma unroll
        for (int i = 0; i < 4; ++i) {
            int c = tid + i * 256;
            int s = c >> 4, dc = (c & 15) * 4;
            float4 val = *(const float4*)(vin + ((size_t)bh * 2048 + s0 + s) * 64 + dc);
            buf[s][dc] = val.x; buf[s][dc + 1] = val.y; buf[s][dc + 2] = val.z; buf[s][dc + 3] = val.w;
        }
        __syncthreads();
#pragma unroll
        for (int i = 0; i < 4; ++i) {
            int c = tid + i * 256;
            int dh = c >> 4, sc = (c & 15) * 4;
            u16x4 o = { f2bf(buf[sc][dh]), f2bf(buf[sc + 1][dh]), f2bf(buf[sc + 2][dh]), f2bf(buf[sc + 3][dh]) };
            *(u16x4*)(vt + ((size_t)bh * 64 + dh) * 2048 + s0 + sc) = o;
        }
    }
}

// ---------------- fused causal flash attention + residual (R10 body + fp32-K staging) ----------------
// grid: (64 bh, 16), qb = 15 - blockIdx.y -> LPT dispatch (longest first, x fastest).
// 256 threads (4 waves) x 32 q-rows = one 128-row q-block per block.
// LDS 51KB -> 3 blocks/CU: 768 slots < 1024 blocks = real backfill queue.
// K staged DIRECTLY from fp32 input (pack4_rhu at ds_write time; loads still
// issued before compute -> async-split preserved). Ps padded to 76 (conflict-free).
// Swapped QK^T & PV; no-max exp2 softmax; deferred l-reduction; vec4 epilogue.
__global__ __launch_bounds__(256, 3) void attn_kernel(const unsigned short* __restrict__ qg,
                                                      const float* __restrict__ kg32,
                                                      const unsigned short* __restrict__ vtg,
                                                      const float* __restrict__ x,
                                                      float* __restrict__ outp) {
    __shared__ __align__(16) unsigned short Ks[2][64][64];
    __shared__ __align__(16) unsigned short VTs[2][64][64];
    __shared__ __align__(16) unsigned short Ps[4][32][76];

    const int bh = blockIdx.x;
    const int qb = 15 - blockIdx.y;
    const int b = bh >> 4, h = bh & 15;
    const int tid = threadIdx.x;
    const int wave = tid >> 6, lane = tid & 63;
    const int lg = lane >> 4, lc = lane & 15;
    const int lc7 = lc & 7;
    const int qw0 = qb * 128 + wave * 32;
    const int nkv = 2 * qb + 2;

    // staging: 256 threads cover 512 chunks of K and VT (2 rows each, same c16)
    const int r0  = tid >> 3;            // 0..31
    const int c16 = tid & 7;
    const int swz = (c16 ^ (r0 & 7)) * 8;    // same for r0+32 (low 3 bits equal)
    const float* kbase = kg32 + ((size_t)bh * 2048 + r0) * 64 + c16 * 8;
    const unsigned short* vbase = vtg + ((size_t)bh * 64 + r0) * 2048 + c16 * 8;

    // Q B-frags in registers: qf[qt][c] = Q[qw0+qt*16+lc][c*32 + lg*8 ..]
    bf16x8 qf[2][2];
#pragma unroll
    for (int qt = 0; qt < 2; ++qt)
#pragma unroll
        for (int c = 0; c < 2; ++c)
            qf[qt][c] = *(const bf16x8*)(qg + ((size_t)bh * 2048 + qw0 + qt * 16 + lc) * 64 + c * 32 + lg * 8);

    f32x4 oacc[2][4];   // O^T: col=lc=q-local, row=lg*4+r=dh-local
#pragma unroll
    for (int qt = 0; qt < 2; ++qt)
#pragma unroll
        for (int dt = 0; dt < 4; ++dt) oacc[qt][dt] = (f32x4){0.f, 0.f, 0.f, 0.f};
    float l_r[2] = {0.f, 0.f};   // lane-local partials; cross-group reduce in epilogue

    {   // prologue: stage tile 0 into buffer 0 (K converted fp32->bf16 here)
        union { uint2 u[2]; bf16x8 v; } cka, ckb;
        cka.u[0] = pack4_rhu(*(const float4*)(kbase));
        cka.u[1] = pack4_rhu(*(const float4*)(kbase + 4));
        ckb.u[0] = pack4_rhu(*(const float4*)(kbase + 2048));
        ckb.u[1] = pack4_rhu(*(const float4*)(kbase + 2052));
        *(bf16x8*)&Ks[0][r0][swz]       = cka.v;
        *(bf16x8*)&Ks[0][r0 + 32][swz]  = ckb.v;
        *(bf16x8*)&VTs[0][r0][swz]      = *(const bf16x8*)(vbase);
        *(bf16x8*)&VTs[0][r0 + 32][swz] = *(const bf16x8*)(vbase + 65536);
    }

    int cur = 0;
    for (int kv = 0; kv < nkv; ++kv) {
        __syncthreads();   // buf[cur] staged & visible; buf[cur^1] readers done

        const bool havenext = (kv + 1 < nkv);
        const int nxt = havenext ? kv + 1 : kv;
        // issue next-tile loads early (latency hides under compute)
        float4 nka0 = *(const float4*)(kbase + (size_t)nxt * 4096);
        float4 nka1 = *(const float4*)(kbase + (size_t)nxt * 4096 + 4);
        float4 nkb0 = *(const float4*)(kbase + (size_t)nxt * 4096 + 2048);
        float4 nkb1 = *(const float4*)(kbase + (size_t)nxt * 4096 + 2052);
        bf16x8 nv0 = *(const bf16x8*)(vbase + nxt * 64);
        bf16x8 nv1 = *(const bf16x8*)(vbase + nxt * 64 + 65536);

        const bool active = (kv * 64 <= qw0 + 31);
        if (active) {
            // K A-frags (shared across both q-tiles)
            bf16x8 kf[4][2];
#pragma unroll
            for (int kt = 0; kt < 4; ++kt)
#pragma unroll
                for (int c = 0; c < 2; ++c)
                    kf[kt][c] = *(const bf16x8*)&Ks[cur][kt * 16 + lc][((4 * c + lg) ^ lc7) * 8];

            const int kvb = kv * 64;
            // ---- per q-tile: S^T = K Q^T (8 MFMA), softmax, pack -> Ps ----
#pragma unroll
            for (int qt = 0; qt < 2; ++qt) {
                f32x4 st[4];
                __builtin_amdgcn_s_setprio(1);
#pragma unroll
                for (int kt = 0; kt < 4; ++kt) {
                    f32x4 a = (f32x4){0.f, 0.f, 0.f, 0.f};
                    a = MFMA16(kf[kt][0], qf[qt][0], a);
                    a = MFMA16(kf[kt][1], qf[qt][1], a);
                    st[kt] = a;
                }
                __builtin_amdgcn_s_setprio(0);

                float pp[4][4];
#pragma unroll
                for (int kt = 0; kt < 4; ++kt)
#pragma unroll
                    for (int r = 0; r < 4; ++r) pp[kt][r] = st[kt][r];
                if (kvb + 63 > qw0 + qt * 16) {   // diagonal tile only
                    const int qrow = qw0 + qt * 16 + lc;
#pragma unroll
                    for (int kt = 0; kt < 4; ++kt)
#pragma unroll
                        for (int r = 0; r < 4; ++r) {
                            int kk = kvb + kt * 16 + lg * 4 + r;
                            if (kk > qrow) pp[kt][r] = -1e30f;
                        }
                }
                float rs = 0.f;
#pragma unroll
                for (int kt = 0; kt < 4; ++kt)
#pragma unroll
                    for (int r = 0; r < 4; ++r) {
                        float e = exp2_fast(pp[kt][r]);
                        pp[kt][r] = e;
                        rs += e;
                    }
                l_r[qt] += rs;
#pragma unroll
                for (int kt = 0; kt < 4; ++kt) {
                    uint2 w;
                    w.x = __builtin_amdgcn_perm(__float_as_uint(pp[kt][1]), __float_as_uint(pp[kt][0]), 0x07060302u);
                    w.y = __builtin_amdgcn_perm(__float_as_uint(pp[kt][3]), __float_as_uint(pp[kt][2]), 0x07060302u);
                    *(uint2*)&Ps[wave][qt * 16 + lc][kt * 16 + lg * 4] = w;
                }
            }
            asm volatile("s_waitcnt lgkmcnt(0)" ::: "memory");

            // ---- O^T += V^T P^T : 16 MFMA, vtf shared across q-tiles ----
            bf16x8 pf[2][2];
#pragma unroll
            for (int qt = 0; qt < 2; ++qt)
#pragma unroll
                for (int c = 0; c < 2; ++c)
                    pf[qt][c] = *(const bf16x8*)&Ps[wave][qt * 16 + lc][c * 32 + lg * 8];
            __builtin_amdgcn_s_setprio(1);
#pragma unroll
            for (int dt = 0; dt < 4; ++dt)
#pragma unroll
                for (int c = 0; c < 2; ++c) {
                    bf16x8 vtf = *(const bf16x8*)&VTs[cur][dt * 16 + lc][((4 * c + lg) ^ lc7) * 8];
#pragma unroll
                    for (int qt = 0; qt < 2; ++qt)
                        oacc[qt][dt] = MFMA16(vtf, pf[qt][c], oacc[qt][dt]);
                }
            __builtin_amdgcn_s_setprio(0);
        }

        // write next tile into the other buffer (pack K fp32->bf16 here)
        if (havenext) {
            union { uint2 u[2]; bf16x8 v; } cka, ckb;
            cka.u[0] = pack4_rhu(nka0);
            cka.u[1] = pack4_rhu(nka1);
            ckb.u[0] = pack4_rhu(nkb0);
            ckb.u[1] = pack4_rhu(nkb1);
            *(bf16x8*)&Ks[cur ^ 1][r0][swz]       = cka.v;
            *(bf16x8*)&Ks[cur ^ 1][r0 + 32][swz]  = ckb.v;
            *(bf16x8*)&VTs[cur ^ 1][r0][swz]      = nv0;
            *(bf16x8*)&VTs[cur ^ 1][r0 + 32][swz] = nv1;
        }
        cur ^= 1;
    }

    // epilogue: finish l reduction, normalize, add residual, vec4 store
#pragma unroll
    for (int qt = 0; qt < 2; ++qt) {
        float lt = l_r[qt];
        lt += __shfl_xor(lt, 16, 64);
        lt += __shfl_xor(lt, 32, 64);
        float li = 1.0f / lt;
        const int q = qw0 + qt * 16 + lc;
        const size_t obase = ((size_t)b * 2048 + q) * 1024 + (size_t)h * 64 + lg * 4;
#pragma unroll
        for (int dt = 0; dt < 4; ++dt) {
            const size_t oi = obase + dt * 16;
            float4 xv = *(const float4*)(x + oi);
            float4 ov;
            ov.x = xv.x + oacc[qt][dt][0] * li;
            ov.y = xv.y + oacc[qt][dt][1] * li;
            ov.z = xv.z + oacc[qt][dt][2] * li;
            ov.w = xv.w + oacc[qt][dt][3] * li;
            *(float4*)(outp + oi) = ov;
        }
    }
}

extern "C" void kernel_launch(void* const* d_in, const int* in_sizes, int n_in,
                              void* d_out, int out_size, void* d_ws, size_t ws_size,
                              hipStream_t stream) {
    const float* x  = (const float*)d_in[0];
    const float* k  = (const float*)d_in[1];
    const float* v  = (const float*)d_in[2];
    const float* wq = (const float*)d_in[3];
    float* outp = (float*)d_out;

    const size_t NELEM = (size_t)4 * 2048 * 1024;
    unsigned short* qbuf  = (unsigned short*)d_ws;
    unsigned short* vtbuf = qbuf + NELEM;

    // merged prep: 512 qproj + 2048 v-trans (k-conversion eliminated)
    prep_kernel<<<512 + 2048, 256, 0, stream>>>(x, wq, v, qbuf, vtbuf);
    attn_kernel<<<dim3(64, 16), 256, 0, stream>>>(qbuf, k, vtbuf, x, outp);
}